// Round 16
// baseline (986.916 us; speedup 1.0000x reference)
//
#include <hip/hip_runtime.h>

#define N_AUTHOR 100000
#define N_FOS    30000
#define N_INST   8000
#define N_PAPER  200000
#define NCNT     838000
#define ETOT     3300000
#define NSHARD   (NCNT / 8)
#define NROWS    338000
#define NBLK_S   661          // ceil(338000/512)

#define NBA 1563
#define NBF 469
#define NBI 125
#define NBP 3125
#define NB_TOTAL (NBP + NBA + NBF + NBI)

#define B_AFF    0
#define B_ITA    8000
#define B_WRITES 108000
#define B_PTA    308000
#define B_CITES  408000
#define B_TOPIC  608000
#define B_FTP    638000

#define OB_A 0
#define OB_F 100000
#define OB_I 130000
#define OB_P 138000

typedef __attribute__((ext_vector_type(8))) short short8v;
typedef __attribute__((ext_vector_type(4))) float float4v;
typedef unsigned short us;

__device__ __forceinline__ us f2bf(float f) {
  unsigned u = __float_as_uint(f);
  u = u + 0x7fffu + ((u >> 16) & 1u);
  return (us)(u >> 16);
}
#define BF2F(s) __uint_as_float(((unsigned)(us)(s)) << 16)

__device__ __forceinline__ void acc8(float4v& x, float4v& y, short8v h) {
  x[0] += BF2F(h[0]); x[1] += BF2F(h[1]); x[2] += BF2F(h[2]); x[3] += BF2F(h[3]);
  y[0] += BF2F(h[4]); y[1] += BF2F(h[5]); y[2] += BF2F(h[6]); y[3] += BF2F(h[7]);
}

__device__ __forceinline__ short8v pack8(float4v a, float4v b) {
  short8v h;
  h[0] = (short)f2bf(a[0]); h[1] = (short)f2bf(a[1]);
  h[2] = (short)f2bf(a[2]); h[3] = (short)f2bf(a[3]);
  h[4] = (short)f2bf(b[0]); h[5] = (short)f2bf(b[1]);
  h[6] = (short)f2bf(b[2]); h[7] = (short)f2bf(b[3]);
  return h;
}

// ---------------- workspace layout (bytes) ----------------
#define O_CNT    0
#define O_OFFS   3352000
#define O_CURSOR 6704000
#define O_BTOT   10056000
#define O_CSR    10060096
#define O_WT     23260096
#define XB_AUTHOR 23620544
#define XB_FOS    49220544
#define XB_INST   56900544
#define XB_PAPER  58948544
#define O_ORDER  110148544
#define O_KEYB   111500544
#define O_BH     111838560
#define O_BB     112515424
#define WS_NEED_BF 113192288ULL

struct RelTab { const int* src; const int* dst; int E; int base; };
struct Rels { RelTab r[7]; };
struct WPtrs { const float* w[11]; };
struct XCvt { const float* x; us* xb; int n8; };

// prep: W transpose+bf16, x fp32->bf16, XCD-sharded edge counting.
__global__ __launch_bounds__(256, 8) void prep(WPtrs P, us* __restrict__ wt,
                     int* __restrict__ cnt,
                     XCvt x0, XCvt x1, XCvt x2, XCvt x3,
                     Rels R, int doX) {
  int gsz = gridDim.x * blockDim.x;
  int gtid = blockIdx.x * blockDim.x + threadIdx.x;
  for (int i = gtid; i < 11 * 16384; i += gsz) {
    int mat = i >> 14, rem = i & 16383;
    int k = rem >> 7, n = rem & 127;
    wt[mat * 16384 + n * 128 + k] = f2bf(P.w[mat][rem]);
  }
  if (doX) {
    XCvt xc[4] = {x0, x1, x2, x3};
    #pragma unroll
    for (int a = 0; a < 4; ++a) {
      const float* xp = xc[a].x;
      short8v* xbp = (short8v*)xc[a].xb;
      int n8 = xc[a].n8;
      for (int i = gtid; i < n8; i += gsz) {
        float4v v0 = *(const float4v*)(xp + (size_t)i * 8);
        float4v v1 = *(const float4v*)(xp + (size_t)i * 8 + 4);
        xbp[i] = pack8(v0, v1);
      }
    }
  }
  const int cls = blockIdx.x & 7;
  const int lo = cls * NSHARD;
  const int hi = lo + NSHARD;
  const int sgsz = (gridDim.x >> 3) * 256;
  const int sgtid = (blockIdx.x >> 3) * 256 + threadIdx.x;
  #pragma unroll
  for (int rr = 0; rr < 7; ++rr) {
    const int* __restrict__ dst = R.r[rr].dst;
    const int E = R.r[rr].E, base = R.r[rr].base;
    for (int e = sgtid; e < E; e += sgsz) {
      int gd = base + dst[e];
      if (gd >= lo && gd < hi) atomicAdd(&cnt[gd], 1);
    }
  }
}

// ------- degree-bucket sort (contention-free counting sort, 256 bins) -------
__global__ __launch_bounds__(256) void ks_hist(const int* __restrict__ cnt,
                                               unsigned char* __restrict__ keyb,
                                               int* __restrict__ bh) {
  __shared__ int lh[256];
  lh[threadIdx.x] = 0;
  __syncthreads();
  #pragma unroll
  for (int r = 0; r < 2; ++r) {
    int u = blockIdx.x * 512 + r * 256 + threadIdx.x;
    if (u < NROWS) {
      int t, loc, key;
      if (u < 100000)      { t = 0; loc = u;          key = cnt[B_ITA + loc] + cnt[B_PTA + loc]; }
      else if (u < 130000) { t = 1; loc = u - 100000; key = cnt[B_TOPIC + loc]; }
      else if (u < 138000) { t = 2; loc = u - 130000; key = cnt[B_AFF + loc]; }
      else                 { t = 3; loc = u - 138000; key = cnt[B_WRITES + loc] + cnt[B_CITES + loc] + cnt[B_FTP + loc]; }
      int k = (key > 63) ? 63 : key;
      int bin = t * 64 + k;
      keyb[u] = (unsigned char)bin;
      atomicAdd(&lh[bin], 1);
    }
  }
  __syncthreads();
  bh[blockIdx.x * 256 + threadIdx.x] = lh[threadIdx.x];
}

__global__ void hscan(const int* __restrict__ bh, int* __restrict__ bb, int nblk) {
  __shared__ int sh[256];
  const int b = threadIdx.x;
  int s = 0;
  int B = 0;
  for (; B + 8 <= nblk; B += 8) {
    int v[8];
    #pragma unroll
    for (int q = 0; q < 8; ++q) v[q] = bh[(B + q) * 256 + b];
    #pragma unroll
    for (int q = 0; q < 8; ++q) { bb[(B + q) * 256 + b] = s; s += v[q]; }
  }
  for (; B < nblk; ++B) { int v = bh[B * 256 + b]; bb[B * 256 + b] = s; s += v; }
  int tot = s;
  sh[b] = s;
  __syncthreads();
  for (int off = 1; off < 256; off <<= 1) {
    int t = (b >= off) ? sh[b - off] : 0;
    __syncthreads();
    sh[b] += t;
    __syncthreads();
  }
  int excl = sh[b] - tot;
  for (B = 0; B < nblk; ++B) bb[B * 256 + b] += excl;
}

__global__ __launch_bounds__(256) void ks_scat(const unsigned char* __restrict__ keyb,
                                               const int* __restrict__ bb,
                                               int* __restrict__ order) {
  __shared__ int lc[256];
  lc[threadIdx.x] = 0;
  __syncthreads();
  #pragma unroll
  for (int r = 0; r < 2; ++r) {
    int u = blockIdx.x * 512 + r * 256 + threadIdx.x;
    if (u < NROWS) {
      int bin = keyb[u];
      int off = atomicAdd(&lc[bin], 1);
      int loc = (u < 100000) ? u : (u < 130000) ? u - 100000
              : (u < 138000) ? u - 130000 : u - 138000;
      order[bb[blockIdx.x * 256 + bin] + off] = loc;
    }
  }
}

__global__ void scan1(const int* __restrict__ cnt, int* __restrict__ offs,
                      int* __restrict__ btot, int n) {
  __shared__ int sh[256];
  int tid = threadIdx.x;
  int base = blockIdx.x * 2048 + tid * 8;
  int v[8]; int s = 0;
  #pragma unroll
  for (int i = 0; i < 8; ++i) { v[i] = (base + i < n) ? cnt[base + i] : 0; s += v[i]; }
  sh[tid] = s; __syncthreads();
  for (int off = 1; off < 256; off <<= 1) {
    int t = (tid >= off) ? sh[tid - off] : 0;
    __syncthreads();
    sh[tid] += t;
    __syncthreads();
  }
  int excl = sh[tid] - s;
  if (tid == 255) btot[blockIdx.x] = sh[255];
  int run = excl;
  #pragma unroll
  for (int i = 0; i < 8; ++i) { if (base + i < n) offs[base + i] = run; run += v[i]; }
}

__global__ void scan23(int* __restrict__ offs, int* __restrict__ cursor,
                       const int* __restrict__ btot, int nb, int n) {
  __shared__ int sh[512];
  int tid = threadIdx.x;
  int v = (tid < nb) ? btot[tid] : 0;
  sh[tid] = v; __syncthreads();
  for (int off = 1; off < 512; off <<= 1) {
    int t = (tid >= off) ? sh[tid - off] : 0;
    __syncthreads();
    sh[tid] += t;
    __syncthreads();
  }
  int excl = sh[tid] - v;
  __syncthreads();
  sh[tid] = excl;
  __syncthreads();
  int gsz = gridDim.x * 512;
  for (int idx = blockIdx.x * 512 + tid; idx < n; idx += gsz) {
    int val = offs[idx] + sh[idx >> 11];
    offs[idx] = val;
    cursor[idx] = val;
  }
}

__global__ __launch_bounds__(256, 8) void fill_sh(Rels R, int* __restrict__ cursor,
                                                  int* __restrict__ csr) {
  const int cls = blockIdx.x & 7;
  const int lo = cls * NSHARD;
  const int hi = lo + NSHARD;
  const int gsz = (gridDim.x >> 3) * 256;
  const int gtid = (blockIdx.x >> 3) * 256 + threadIdx.x;
  #pragma unroll
  for (int rr = 0; rr < 7; ++rr) {
    const int* __restrict__ src = R.r[rr].src;
    const int* __restrict__ dst = R.r[rr].dst;
    const int E = R.r[rr].E, base = R.r[rr].base;
    for (int e = gtid; e < E; e += gsz) {
      int gd = base + dst[e];
      if (gd >= lo && gd < hi) {
        int p = atomicAdd(&cursor[gd], 1);
        csr[p] = src[e];
      }
    }
  }
}

// -------- fused gather-GEMM body: R12 2-edge loop + degree-sorted rows ------
template <int NSRC>
__device__ __forceinline__ void fused_body(
    const us* __restrict__ x0, const us* __restrict__ x1,
    const us* __restrict__ x2, const us* __restrict__ x3,
    const us* __restrict__ w0, const us* __restrict__ w1,
    const us* __restrict__ w2, const us* __restrict__ w3,
    int b1, int b2, int b3,
    const int* __restrict__ offs, const int* __restrict__ cnt,
    const int* __restrict__ csr, const int* __restrict__ order, int obase,
    const float* __restrict__ bias, float* __restrict__ out, int n, int rb0) {
  const int lane = threadIdx.x & 63;
  const int wv = threadIdx.x >> 6;
  const int rb = rb0 + wv * 16;
  int slot = rb + (lane & 15); if (slot >= n) slot = n - 1;
  const int g = order[obase + slot];          // degree-sorted row
  const int cw = (lane >> 4) * 8;

  const us* xs[4] = {x0, x1, x2, x3};
  const us* wsp[4] = {w0, w1, w2, w3};
  const int bases[4] = {0, b1, b2, b3};

  float4v acc[8];
  #pragma unroll
  for (int i = 0; i < 8; ++i) acc[i] = (float4v)0.0f;

  #pragma unroll
  for (int kb = 0; kb < NSRC; ++kb) {
    short8v af[4];
    if (kb == 0) {
      const us* rp = xs[0] + (size_t)g * 128 + cw;
      #pragma unroll
      for (int ks = 0; ks < 4; ++ks)
        af[ks] = *(const short8v*)(rp + ks * 32);
    } else {
      int gd = bases[kb] + g;
      int st = offs[gd];
      int deg = cnt[gd];
      const us* xb = xs[kb];
      float4v a0[4], a1[4];
      #pragma unroll
      for (int ks = 0; ks < 4; ++ks) { a0[ks] = (float4v)0.f; a1[ks] = (float4v)0.f; }
      int j = 0;
      for (; j + 2 <= deg; j += 2) {
        int s0 = csr[st + j], s1 = csr[st + j + 1];
        const us* p0 = xb + (size_t)s0 * 128 + cw;
        const us* p1 = xb + (size_t)s1 * 128 + cw;
        #pragma unroll
        for (int ks = 0; ks < 4; ++ks) {
          short8v h0 = *(const short8v*)(p0 + ks * 32);
          short8v h1 = *(const short8v*)(p1 + ks * 32);
          acc8(a0[ks], a1[ks], h0);
          acc8(a0[ks], a1[ks], h1);
        }
      }
      if (j < deg) {
        int s0 = csr[st + j];
        const us* p0 = xb + (size_t)s0 * 128 + cw;
        #pragma unroll
        for (int ks = 0; ks < 4; ++ks) {
          short8v h0 = *(const short8v*)(p0 + ks * 32);
          acc8(a0[ks], a1[ks], h0);
        }
      }
      float sc = 1.0f / (float)((deg > 0) ? deg : 1);
      #pragma unroll
      for (int ks = 0; ks < 4; ++ks)
        af[ks] = pack8(a0[ks] * sc, a1[ks] * sc);
    }
    const us* wb = wsp[kb] + (size_t)(lane & 15) * 128 + cw;
    #pragma unroll
    for (int ct = 0; ct < 8; ++ct) {
      short8v bfr[4];
      #pragma unroll
      for (int ks = 0; ks < 4; ++ks)
        bfr[ks] = *(const short8v*)(wb + ct * 2048 + ks * 32);
      #pragma unroll
      for (int ks = 0; ks < 4; ++ks)
        acc[ct] = __builtin_amdgcn_mfma_f32_16x16x32_bf16(af[ks], bfr[ks], acc[ct], 0, 0, 0);
    }
  }
  // epilogue: slot -> permuted row lookup (4 rows per lane)
  int grow[4];
  #pragma unroll
  for (int i = 0; i < 4; ++i) {
    int srow = rb + (lane >> 4) * 4 + i;
    grow[i] = (srow < n) ? order[obase + srow] : -1;
  }
  #pragma unroll
  for (int ct = 0; ct < 8; ++ct) {
    #pragma unroll
    for (int i = 0; i < 4; ++i) {
      if (grow[i] >= 0) {
        int col = ct * 16 + (lane & 15);
        out[(size_t)grow[i] * 128 + col] = acc[ct][i] + bias[col];
      }
    }
  }
}

__global__ __launch_bounds__(256, 6) void fused_all(
    const us* __restrict__ xbA, const us* __restrict__ xbF,
    const us* __restrict__ xbI, const us* __restrict__ xbP,
    const us* __restrict__ wt,
    const int* __restrict__ offs, const int* __restrict__ cnt,
    const int* __restrict__ csr, const int* __restrict__ order,
    const float* __restrict__ bA, const float* __restrict__ bF,
    const float* __restrict__ bI, const float* __restrict__ bP,
    float* __restrict__ out) {
  const int bid = blockIdx.x;
  if (bid < NBP) {
    fused_body<4>(xbP, xbA, xbP, xbF,
                  wt + 3 * 16384, wt + 6 * 16384, wt + 8 * 16384, wt + 10 * 16384,
                  B_WRITES, B_CITES, B_FTP, offs, cnt, csr, order, OB_P,
                  bP, out + (size_t)138000 * 128, N_PAPER, bid * 64);
  } else if (bid < NBP + NBA) {
    fused_body<3>(xbA, xbI, xbP, nullptr,
                  wt + 0 * 16384, wt + 5 * 16384, wt + 7 * 16384, nullptr,
                  B_ITA, B_PTA, 0, offs, cnt, csr, order, OB_A,
                  bA, out, N_AUTHOR, (bid - NBP) * 64);
  } else if (bid < NBP + NBA + NBF) {
    fused_body<2>(xbF, xbP, nullptr, nullptr,
                  wt + 1 * 16384, wt + 9 * 16384, nullptr, nullptr,
                  B_TOPIC, 0, 0, offs, cnt, csr, order, OB_F,
                  bF, out + (size_t)100000 * 128, N_FOS, (bid - NBP - NBA) * 64);
  } else {
    fused_body<2>(xbI, xbA, nullptr, nullptr,
                  wt + 2 * 16384, wt + 4 * 16384, nullptr, nullptr,
                  B_AFF, 0, 0, offs, cnt, csr, order, OB_I,
                  bI, out + (size_t)130000 * 128, N_INST, (bid - NBP - NBA - NBF) * 64);
  }
}

// ---------------- fp32 fallback (small ws) ----------------------------------
typedef float4v f4;
__global__ __launch_bounds__(256, 4) void fb_gemm(
    const float* __restrict__ x0, const float* __restrict__ x1,
    const float* __restrict__ x2, const float* __restrict__ x3,
    const us* __restrict__ w0, const us* __restrict__ w1,
    const us* __restrict__ w2, const us* __restrict__ w3,
    int nsrc, int b1, int b2, int b3,
    const int* __restrict__ offs, const int* __restrict__ cnt,
    const int* __restrict__ csr,
    const float* __restrict__ bias, float* __restrict__ out, int n) {
  const int lane = threadIdx.x & 63;
  const int wv = threadIdx.x >> 6;
  const int rb = blockIdx.x * 64 + wv * 16;
  int ar = rb + (lane & 15); if (ar >= n) ar = n - 1;
  const int cw = (lane >> 4) * 8;
  const float* xs[4] = {x0, x1, x2, x3};
  const us* wsp[4] = {w0, w1, w2, w3};
  const int bases[4] = {0, b1, b2, b3};
  float4v acc[8];
  #pragma unroll
  for (int i = 0; i < 8; ++i) acc[i] = (float4v)0.0f;
  for (int kb = 0; kb < nsrc; ++kb) {
    short8v af[4];
    const float* xb = xs[kb];
    if (kb == 0) {
      const float* rp = xb + (size_t)ar * 128 + cw;
      #pragma unroll
      for (int ks = 0; ks < 4; ++ks) {
        f4 u = *(const f4*)(rp + ks * 32);
        f4 v = *(const f4*)(rp + ks * 32 + 4);
        af[ks] = pack8(u, v);
      }
    } else {
      int gd = bases[kb] + ar;
      int st = offs[gd];
      int deg = cnt[gd];
      f4 a0[4], a1[4];
      #pragma unroll
      for (int ks = 0; ks < 4; ++ks) { a0[ks] = (f4)0.f; a1[ks] = (f4)0.f; }
      for (int j = 0; j < deg; ++j) {
        int s0 = csr[st + j];
        const float* p0 = xb + (size_t)s0 * 128 + cw;
        #pragma unroll
        for (int ks = 0; ks < 4; ++ks) {
          a0[ks] += *(const f4*)(p0 + ks * 32);
          a1[ks] += *(const f4*)(p0 + ks * 32 + 4);
        }
      }
      float sc = 1.0f / (float)((deg > 0) ? deg : 1);
      #pragma unroll
      for (int ks = 0; ks < 4; ++ks)
        af[ks] = pack8(a0[ks] * sc, a1[ks] * sc);
    }
    const us* wb = wsp[kb] + (size_t)(lane & 15) * 128 + cw;
    #pragma unroll
    for (int ct = 0; ct < 8; ++ct) {
      short8v bfr[4];
      #pragma unroll
      for (int ks = 0; ks < 4; ++ks)
        bfr[ks] = *(const short8v*)(wb + ct * 2048 + ks * 32);
      #pragma unroll
      for (int ks = 0; ks < 4; ++ks)
        acc[ct] = __builtin_amdgcn_mfma_f32_16x16x32_bf16(af[ks], bfr[ks], acc[ct], 0, 0, 0);
    }
  }
  #pragma unroll
  for (int ct = 0; ct < 8; ++ct) {
    #pragma unroll
    for (int i = 0; i < 4; ++i) {
      int g = rb + (lane >> 4) * 4 + i;
      if (g < n) {
        int col = ct * 16 + (lane & 15);
        out[(size_t)g * 128 + col] = acc[ct][i] + bias[col];
      }
    }
  }
}

extern "C" void kernel_launch(void* const* d_in, const int* in_sizes, int n_in,
                              void* d_out, int out_size, void* d_ws, size_t ws_size,
                              hipStream_t stream) {
  const float* x_author = (const float*)d_in[0];
  const float* x_fos    = (const float*)d_in[1];
  const float* x_inst   = (const float*)d_in[2];
  const float* x_paper  = (const float*)d_in[3];

  Rels R;
  const int E[7]  = {150000, 150000, 500000, 500000, 1000000, 500000, 500000};
  const int ND[7] = {N_INST, N_AUTHOR, N_PAPER, N_AUTHOR, N_PAPER, N_FOS, N_PAPER};
  int base = 0;
  for (int r = 0; r < 7; ++r) {
    R.r[r].src = (const int*)d_in[4 + 2 * r];
    R.r[r].dst = (const int*)d_in[5 + 2 * r];
    R.r[r].E = E[r];
    R.r[r].base = base;
    base += ND[r];
  }

  char* ws = (char*)d_ws;
  int* cnt    = (int*)(ws + O_CNT);
  int* offs   = (int*)(ws + O_OFFS);
  int* cursor = (int*)(ws + O_CURSOR);
  int* btot   = (int*)(ws + O_BTOT);
  int* csr    = (int*)(ws + O_CSR);
  us* wt  = (us*)(ws + O_WT);
  us* xbA = (us*)(ws + XB_AUTHOR);
  us* xbF = (us*)(ws + XB_FOS);
  us* xbI = (us*)(ws + XB_INST);
  us* xbP = (us*)(ws + XB_PAPER);
  int* order = (int*)(ws + O_ORDER);
  unsigned char* keyb = (unsigned char*)(ws + O_KEYB);
  int* bh = (int*)(ws + O_BH);
  int* bb = (int*)(ws + O_BB);

  const int useBF = (ws_size >= WS_NEED_BF) ? 1 : 0;

  WPtrs WP;
  WP.w[0] = (const float*)d_in[18];
  WP.w[1] = (const float*)d_in[20];
  WP.w[2] = (const float*)d_in[22];
  WP.w[3] = (const float*)d_in[24];
  for (int r = 0; r < 7; ++r) WP.w[4 + r] = (const float*)d_in[26 + r];

  XCvt xcA = {x_author, xbA, N_AUTHOR * 16};
  XCvt xcF = {x_fos,    xbF, N_FOS * 16};
  XCvt xcI = {x_inst,   xbI, N_INST * 16};
  XCvt xcP = {x_paper,  xbP, N_PAPER * 16};

  hipMemsetAsync(cnt, 0, (size_t)NCNT * 4, stream);
  prep<<<2048, 256, 0, stream>>>(WP, wt, cnt, xcA, xcF, xcI, xcP, R, useBF);

  float* out = (float*)d_out;
  const float* bA = (const float*)d_in[19];
  const float* bF = (const float*)d_in[21];
  const float* bI = (const float*)d_in[23];
  const float* bP = (const float*)d_in[25];

  if (useBF) {
    // degree-bucket row sort (needs cnt only)
    ks_hist<<<NBLK_S, 256, 0, stream>>>(cnt, keyb, bh);
    hscan<<<1, 256, 0, stream>>>(bh, bb, NBLK_S);
    ks_scat<<<NBLK_S, 256, 0, stream>>>(keyb, bb, order);

    scan1<<<410, 256, 0, stream>>>(cnt, offs, btot, NCNT);
    scan23<<<1024, 512, 0, stream>>>(offs, cursor, btot, 410, NCNT);
    fill_sh<<<2048, 256, 0, stream>>>(R, cursor, csr);

    fused_all<<<NB_TOTAL, 256, 0, stream>>>(xbA, xbF, xbI, xbP, wt,
                                            offs, cnt, csr, order,
                                            bA, bF, bI, bP, out);
  } else {
    scan1<<<410, 256, 0, stream>>>(cnt, offs, btot, NCNT);
    scan23<<<1024, 512, 0, stream>>>(offs, cursor, btot, 410, NCNT);
    fill_sh<<<2048, 256, 0, stream>>>(R, cursor, csr);

    fb_gemm<<<NBA, 256, 0, stream>>>(
        x_author, x_inst, x_paper, nullptr,
        wt + 0 * 16384, wt + 5 * 16384, wt + 7 * 16384, nullptr,
        3, B_ITA, B_PTA, 0, offs, cnt, csr, bA, out, N_AUTHOR);
    fb_gemm<<<NBF, 256, 0, stream>>>(
        x_fos, x_paper, nullptr, nullptr,
        wt + 1 * 16384, wt + 9 * 16384, nullptr, nullptr,
        2, B_TOPIC, 0, 0, offs, cnt, csr, bF, out + (size_t)100000 * 128, N_FOS);
    fb_gemm<<<NBI, 256, 0, stream>>>(
        x_inst, x_author, nullptr, nullptr,
        wt + 2 * 16384, wt + 4 * 16384, nullptr, nullptr,
        2, B_AFF, 0, 0, offs, cnt, csr, bI, out + (size_t)130000 * 128, N_INST);
    fb_gemm<<<NBP, 256, 0, stream>>>(
        x_paper, x_author, x_paper, x_fos,
        wt + 3 * 16384, wt + 6 * 16384, wt + 8 * 16384, wt + 10 * 16384,
        4, B_WRITES, B_CITES, B_FTP, offs, cnt, csr, bP,
        out + (size_t)138000 * 128, N_PAPER);
  }
}

// Round 17
// 846.132 us; speedup vs baseline: 1.1664x; 1.1664x over previous
//
#include <hip/hip_runtime.h>

#define N_AUTHOR 100000
#define N_FOS    30000
#define N_INST   8000
#define N_PAPER  200000
#define NCNT     838000
#define ETOT     3300000
#define NSHARD   (NCNT / 8)

#define NBA 1563
#define NBF 469
#define NBI 125
#define NBP 3125
#define NB_TOTAL (NBP + NBA + NBF + NBI)   // 5282
#define SWZ_Q (NB_TOTAL / 8)               // 660
#define SWZ_R (NB_TOTAL % 8)               // 2

#define B_AFF    0
#define B_ITA    8000
#define B_WRITES 108000
#define B_PTA    308000
#define B_CITES  408000
#define B_TOPIC  608000
#define B_FTP    638000

typedef __attribute__((ext_vector_type(8))) short short8v;
typedef __attribute__((ext_vector_type(4))) float float4v;
typedef unsigned short us;

__device__ __forceinline__ us f2bf(float f) {
  unsigned u = __float_as_uint(f);
  u = u + 0x7fffu + ((u >> 16) & 1u);
  return (us)(u >> 16);
}
#define BF2F(s) __uint_as_float(((unsigned)(us)(s)) << 16)

__device__ __forceinline__ void acc8(float4v& x, float4v& y, short8v h) {
  x[0] += BF2F(h[0]); x[1] += BF2F(h[1]); x[2] += BF2F(h[2]); x[3] += BF2F(h[3]);
  y[0] += BF2F(h[4]); y[1] += BF2F(h[5]); y[2] += BF2F(h[6]); y[3] += BF2F(h[7]);
}

__device__ __forceinline__ short8v pack8(float4v a, float4v b) {
  short8v h;
  h[0] = (short)f2bf(a[0]); h[1] = (short)f2bf(a[1]);
  h[2] = (short)f2bf(a[2]); h[3] = (short)f2bf(a[3]);
  h[4] = (short)f2bf(b[0]); h[5] = (short)f2bf(b[1]);
  h[6] = (short)f2bf(b[2]); h[7] = (short)f2bf(b[3]);
  return h;
}

// ---------------- workspace layout (bytes) ----------------
#define O_CNT    0
#define O_OFFS   3352000
#define O_CURSOR 6704000
#define O_BTOT   10056000
#define O_CSR    10060096
#define O_WT     23260096
#define XB_AUTHOR 23620544
#define XB_FOS    49220544
#define XB_INST   56900544
#define XB_PAPER  58948544
#define WS_NEED_BF 110148544ULL

struct RelTab { const int* src; const int* dst; int E; int base; };
struct Rels { RelTab r[7]; };
struct WPtrs { const float* w[11]; };
struct XCvt { const float* x; us* xb; int n8; };

// prep: W transpose+bf16, x fp32->bf16, XCD-sharded edge counting.
__global__ __launch_bounds__(256, 8) void prep(WPtrs P, us* __restrict__ wt,
                     int* __restrict__ cnt,
                     XCvt x0, XCvt x1, XCvt x2, XCvt x3,
                     Rels R, int doX) {
  int gsz = gridDim.x * blockDim.x;
  int gtid = blockIdx.x * blockDim.x + threadIdx.x;
  for (int i = gtid; i < 11 * 16384; i += gsz) {
    int mat = i >> 14, rem = i & 16383;
    int k = rem >> 7, n = rem & 127;
    wt[mat * 16384 + n * 128 + k] = f2bf(P.w[mat][rem]);
  }
  if (doX) {
    XCvt xc[4] = {x0, x1, x2, x3};
    #pragma unroll
    for (int a = 0; a < 4; ++a) {
      const float* xp = xc[a].x;
      short8v* xbp = (short8v*)xc[a].xb;
      int n8 = xc[a].n8;
      for (int i = gtid; i < n8; i += gsz) {
        float4v v0 = *(const float4v*)(xp + (size_t)i * 8);
        float4v v1 = *(const float4v*)(xp + (size_t)i * 8 + 4);
        xbp[i] = pack8(v0, v1);
      }
    }
  }
  const int cls = blockIdx.x & 7;
  const int lo = cls * NSHARD;
  const int hi = lo + NSHARD;
  const int sgsz = (gridDim.x >> 3) * 256;
  const int sgtid = (blockIdx.x >> 3) * 256 + threadIdx.x;
  #pragma unroll
  for (int rr = 0; rr < 7; ++rr) {
    const int* __restrict__ dst = R.r[rr].dst;
    const int E = R.r[rr].E, base = R.r[rr].base;
    for (int e = sgtid; e < E; e += sgsz) {
      int gd = base + dst[e];
      if (gd >= lo && gd < hi) atomicAdd(&cnt[gd], 1);
    }
  }
}

__global__ void scan1(const int* __restrict__ cnt, int* __restrict__ offs,
                      int* __restrict__ btot, int n) {
  __shared__ int sh[256];
  int tid = threadIdx.x;
  int base = blockIdx.x * 2048 + tid * 8;
  int v[8]; int s = 0;
  #pragma unroll
  for (int i = 0; i < 8; ++i) { v[i] = (base + i < n) ? cnt[base + i] : 0; s += v[i]; }
  sh[tid] = s; __syncthreads();
  for (int off = 1; off < 256; off <<= 1) {
    int t = (tid >= off) ? sh[tid - off] : 0;
    __syncthreads();
    sh[tid] += t;
    __syncthreads();
  }
  int excl = sh[tid] - s;
  if (tid == 255) btot[blockIdx.x] = sh[255];
  int run = excl;
  #pragma unroll
  for (int i = 0; i < 8; ++i) { if (base + i < n) offs[base + i] = run; run += v[i]; }
}

__global__ void scan23(int* __restrict__ offs, int* __restrict__ cursor,
                       const int* __restrict__ btot, int nb, int n) {
  __shared__ int sh[512];
  int tid = threadIdx.x;
  int v = (tid < nb) ? btot[tid] : 0;
  sh[tid] = v; __syncthreads();
  for (int off = 1; off < 512; off <<= 1) {
    int t = (tid >= off) ? sh[tid - off] : 0;
    __syncthreads();
    sh[tid] += t;
    __syncthreads();
  }
  int excl = sh[tid] - v;
  __syncthreads();
  sh[tid] = excl;
  __syncthreads();
  int gsz = gridDim.x * 512;
  for (int idx = blockIdx.x * 512 + tid; idx < n; idx += gsz) {
    int val = offs[idx] + sh[idx >> 11];
    offs[idx] = val;
    cursor[idx] = val;
  }
}

__global__ __launch_bounds__(256, 8) void fill_sh(Rels R, int* __restrict__ cursor,
                                                  int* __restrict__ csr) {
  const int cls = blockIdx.x & 7;
  const int lo = cls * NSHARD;
  const int hi = lo + NSHARD;
  const int gsz = (gridDim.x >> 3) * 256;
  const int gtid = (blockIdx.x >> 3) * 256 + threadIdx.x;
  #pragma unroll
  for (int rr = 0; rr < 7; ++rr) {
    const int* __restrict__ src = R.r[rr].src;
    const int* __restrict__ dst = R.r[rr].dst;
    const int E = R.r[rr].E, base = R.r[rr].base;
    for (int e = gtid; e < E; e += gsz) {
      int gd = base + dst[e];
      if (gd >= lo && gd < hi) {
        int p = atomicAdd(&cursor[gd], 1);
        csr[p] = src[e];
      }
    }
  }
}

// -------- fused gather-GEMM body: R12 2-edge batching (proven 466us) --------
template <int NSRC>
__device__ __forceinline__ void fused_body(
    const us* __restrict__ x0, const us* __restrict__ x1,
    const us* __restrict__ x2, const us* __restrict__ x3,
    const us* __restrict__ w0, const us* __restrict__ w1,
    const us* __restrict__ w2, const us* __restrict__ w3,
    int b1, int b2, int b3,
    const int* __restrict__ offs, const int* __restrict__ cnt,
    const int* __restrict__ csr,
    const float* __restrict__ bias, float* __restrict__ out, int n, int rb0) {
  const int lane = threadIdx.x & 63;
  const int wv = threadIdx.x >> 6;
  const int rb = rb0 + wv * 16;
  int ar = rb + (lane & 15); if (ar >= n) ar = n - 1;
  const int cw = (lane >> 4) * 8;

  const us* xs[4] = {x0, x1, x2, x3};
  const us* wsp[4] = {w0, w1, w2, w3};
  const int bases[4] = {0, b1, b2, b3};

  float4v acc[8];
  #pragma unroll
  for (int i = 0; i < 8; ++i) acc[i] = (float4v)0.0f;

  #pragma unroll
  for (int kb = 0; kb < NSRC; ++kb) {
    short8v af[4];
    if (kb == 0) {
      const us* rp = xs[0] + (size_t)ar * 128 + cw;
      #pragma unroll
      for (int ks = 0; ks < 4; ++ks)
        af[ks] = *(const short8v*)(rp + ks * 32);
    } else {
      int gd = bases[kb] + ar;
      int st = offs[gd];
      int deg = cnt[gd];
      const us* xb = xs[kb];
      float4v a0[4], a1[4];
      #pragma unroll
      for (int ks = 0; ks < 4; ++ks) { a0[ks] = (float4v)0.f; a1[ks] = (float4v)0.f; }
      int j = 0;
      for (; j + 2 <= deg; j += 2) {
        int s0 = csr[st + j], s1 = csr[st + j + 1];
        const us* p0 = xb + (size_t)s0 * 128 + cw;
        const us* p1 = xb + (size_t)s1 * 128 + cw;
        #pragma unroll
        for (int ks = 0; ks < 4; ++ks) {
          short8v h0 = *(const short8v*)(p0 + ks * 32);
          short8v h1 = *(const short8v*)(p1 + ks * 32);
          acc8(a0[ks], a1[ks], h0);
          acc8(a0[ks], a1[ks], h1);
        }
      }
      if (j < deg) {
        int s0 = csr[st + j];
        const us* p0 = xb + (size_t)s0 * 128 + cw;
        #pragma unroll
        for (int ks = 0; ks < 4; ++ks) {
          short8v h0 = *(const short8v*)(p0 + ks * 32);
          acc8(a0[ks], a1[ks], h0);
        }
      }
      float sc = 1.0f / (float)((deg > 0) ? deg : 1);
      #pragma unroll
      for (int ks = 0; ks < 4; ++ks)
        af[ks] = pack8(a0[ks] * sc, a1[ks] * sc);
    }
    const us* wb = wsp[kb] + (size_t)(lane & 15) * 128 + cw;
    #pragma unroll
    for (int ct = 0; ct < 8; ++ct) {
      short8v bfr[4];
      #pragma unroll
      for (int ks = 0; ks < 4; ++ks)
        bfr[ks] = *(const short8v*)(wb + ct * 2048 + ks * 32);
      #pragma unroll
      for (int ks = 0; ks < 4; ++ks)
        acc[ct] = __builtin_amdgcn_mfma_f32_16x16x32_bf16(af[ks], bfr[ks], acc[ct], 0, 0, 0);
    }
  }
  #pragma unroll
  for (int ct = 0; ct < 8; ++ct) {
    #pragma unroll
    for (int i = 0; i < 4; ++i) {
      int g = rb + (lane >> 4) * 4 + i;
      if (g < n) {
        int col = ct * 16 + (lane & 15);
        out[(size_t)g * 128 + col] = acc[ct][i] + bias[col];
      }
    }
  }
}

// merged launch with bijective XCD-aware swizzle (m204 formula)
__global__ __launch_bounds__(256, 6) void fused_all(
    const us* __restrict__ xbA, const us* __restrict__ xbF,
    const us* __restrict__ xbI, const us* __restrict__ xbP,
    const us* __restrict__ wt,
    const int* __restrict__ offs, const int* __restrict__ cnt,
    const int* __restrict__ csr,
    const float* __restrict__ bA, const float* __restrict__ bF,
    const float* __restrict__ bI, const float* __restrict__ bP,
    float* __restrict__ out) {
  const int orig = blockIdx.x;
  const int xcd = orig & 7;
  const int idx = orig >> 3;
  const int bid = ((xcd < SWZ_R) ? xcd * (SWZ_Q + 1)
                                 : SWZ_R * (SWZ_Q + 1) + (xcd - SWZ_R) * SWZ_Q) + idx;
  if (bid < NBP) {
    fused_body<4>(xbP, xbA, xbP, xbF,
                  wt + 3 * 16384, wt + 6 * 16384, wt + 8 * 16384, wt + 10 * 16384,
                  B_WRITES, B_CITES, B_FTP, offs, cnt, csr,
                  bP, out + (size_t)138000 * 128, N_PAPER, bid * 64);
  } else if (bid < NBP + NBA) {
    fused_body<3>(xbA, xbI, xbP, nullptr,
                  wt + 0 * 16384, wt + 5 * 16384, wt + 7 * 16384, nullptr,
                  B_ITA, B_PTA, 0, offs, cnt, csr,
                  bA, out, N_AUTHOR, (bid - NBP) * 64);
  } else if (bid < NBP + NBA + NBF) {
    fused_body<2>(xbF, xbP, nullptr, nullptr,
                  wt + 1 * 16384, wt + 9 * 16384, nullptr, nullptr,
                  B_TOPIC, 0, 0, offs, cnt, csr,
                  bF, out + (size_t)100000 * 128, N_FOS, (bid - NBP - NBA) * 64);
  } else {
    fused_body<2>(xbI, xbA, nullptr, nullptr,
                  wt + 2 * 16384, wt + 4 * 16384, nullptr, nullptr,
                  B_AFF, 0, 0, offs, cnt, csr,
                  bI, out + (size_t)130000 * 128, N_INST, (bid - NBP - NBA - NBF) * 64);
  }
}

// ---------------- fp32 fallback (small ws) ----------------------------------
typedef float4v f4;
__global__ __launch_bounds__(256, 4) void fb_gemm(
    const float* __restrict__ x0, const float* __restrict__ x1,
    const float* __restrict__ x2, const float* __restrict__ x3,
    const us* __restrict__ w0, const us* __restrict__ w1,
    const us* __restrict__ w2, const us* __restrict__ w3,
    int nsrc, int b1, int b2, int b3,
    const int* __restrict__ offs, const int* __restrict__ cnt,
    const int* __restrict__ csr,
    const float* __restrict__ bias, float* __restrict__ out, int n) {
  const int lane = threadIdx.x & 63;
  const int wv = threadIdx.x >> 6;
  const int rb = blockIdx.x * 64 + wv * 16;
  int ar = rb + (lane & 15); if (ar >= n) ar = n - 1;
  const int cw = (lane >> 4) * 8;
  const float* xs[4] = {x0, x1, x2, x3};
  const us* wsp[4] = {w0, w1, w2, w3};
  const int bases[4] = {0, b1, b2, b3};
  float4v acc[8];
  #pragma unroll
  for (int i = 0; i < 8; ++i) acc[i] = (float4v)0.0f;
  for (int kb = 0; kb < nsrc; ++kb) {
    short8v af[4];
    const float* xb = xs[kb];
    if (kb == 0) {
      const float* rp = xb + (size_t)ar * 128 + cw;
      #pragma unroll
      for (int ks = 0; ks < 4; ++ks) {
        f4 u = *(const f4*)(rp + ks * 32);
        f4 v = *(const f4*)(rp + ks * 32 + 4);
        af[ks] = pack8(u, v);
      }
    } else {
      int gd = bases[kb] + ar;
      int st = offs[gd];
      int deg = cnt[gd];
      f4 a0[4], a1[4];
      #pragma unroll
      for (int ks = 0; ks < 4; ++ks) { a0[ks] = (f4)0.f; a1[ks] = (f4)0.f; }
      for (int j = 0; j < deg; ++j) {
        int s0 = csr[st + j];
        const float* p0 = xb + (size_t)s0 * 128 + cw;
        #pragma unroll
        for (int ks = 0; ks < 4; ++ks) {
          a0[ks] += *(const f4*)(p0 + ks * 32);
          a1[ks] += *(const f4*)(p0 + ks * 32 + 4);
        }
      }
      float sc = 1.0f / (float)((deg > 0) ? deg : 1);
      #pragma unroll
      for (int ks = 0; ks < 4; ++ks)
        af[ks] = pack8(a0[ks] * sc, a1[ks] * sc);
    }
    const us* wb = wsp[kb] + (size_t)(lane & 15) * 128 + cw;
    #pragma unroll
    for (int ct = 0; ct < 8; ++ct) {
      short8v bfr[4];
      #pragma unroll
      for (int ks = 0; ks < 4; ++ks)
        bfr[ks] = *(const short8v*)(wb + ct * 2048 + ks * 32);
      #pragma unroll
      for (int ks = 0; ks < 4; ++ks)
        acc[ct] = __builtin_amdgcn_mfma_f32_16x16x32_bf16(af[ks], bfr[ks], acc[ct], 0, 0, 0);
    }
  }
  #pragma unroll
  for (int ct = 0; ct < 8; ++ct) {
    #pragma unroll
    for (int i = 0; i < 4; ++i) {
      int g = rb + (lane >> 4) * 4 + i;
      if (g < n) {
        int col = ct * 16 + (lane & 15);
        out[(size_t)g * 128 + col] = acc[ct][i] + bias[col];
      }
    }
  }
}

extern "C" void kernel_launch(void* const* d_in, const int* in_sizes, int n_in,
                              void* d_out, int out_size, void* d_ws, size_t ws_size,
                              hipStream_t stream) {
  const float* x_author = (const float*)d_in[0];
  const float* x_fos    = (const float*)d_in[1];
  const float* x_inst   = (const float*)d_in[2];
  const float* x_paper  = (const float*)d_in[3];

  Rels R;
  const int E[7]  = {150000, 150000, 500000, 500000, 1000000, 500000, 500000};
  const int ND[7] = {N_INST, N_AUTHOR, N_PAPER, N_AUTHOR, N_PAPER, N_FOS, N_PAPER};
  int base = 0;
  for (int r = 0; r < 7; ++r) {
    R.r[r].src = (const int*)d_in[4 + 2 * r];
    R.r[r].dst = (const int*)d_in[5 + 2 * r];
    R.r[r].E = E[r];
    R.r[r].base = base;
    base += ND[r];
  }

  char* ws = (char*)d_ws;
  int* cnt    = (int*)(ws + O_CNT);
  int* offs   = (int*)(ws + O_OFFS);
  int* cursor = (int*)(ws + O_CURSOR);
  int* btot   = (int*)(ws + O_BTOT);
  int* csr    = (int*)(ws + O_CSR);
  us* wt  = (us*)(ws + O_WT);
  us* xbA = (us*)(ws + XB_AUTHOR);
  us* xbF = (us*)(ws + XB_FOS);
  us* xbI = (us*)(ws + XB_INST);
  us* xbP = (us*)(ws + XB_PAPER);

  const int useBF = (ws_size >= WS_NEED_BF) ? 1 : 0;

  WPtrs WP;
  WP.w[0] = (const float*)d_in[18];
  WP.w[1] = (const float*)d_in[20];
  WP.w[2] = (const float*)d_in[22];
  WP.w[3] = (const float*)d_in[24];
  for (int r = 0; r < 7; ++r) WP.w[4 + r] = (const float*)d_in[26 + r];

  XCvt xcA = {x_author, xbA, N_AUTHOR * 16};
  XCvt xcF = {x_fos,    xbF, N_FOS * 16};
  XCvt xcI = {x_inst,   xbI, N_INST * 16};
  XCvt xcP = {x_paper,  xbP, N_PAPER * 16};

  hipMemsetAsync(cnt, 0, (size_t)NCNT * 4, stream);
  prep<<<2048, 256, 0, stream>>>(WP, wt, cnt, xcA, xcF, xcI, xcP, R, useBF);
  scan1<<<410, 256, 0, stream>>>(cnt, offs, btot, NCNT);
  scan23<<<1024, 512, 0, stream>>>(offs, cursor, btot, 410, NCNT);
  fill_sh<<<2048, 256, 0, stream>>>(R, cursor, csr);

  float* out = (float*)d_out;
  const float* bA = (const float*)d_in[19];
  const float* bF = (const float*)d_in[21];
  const float* bI = (const float*)d_in[23];
  const float* bP = (const float*)d_in[25];

  if (useBF) {
    fused_all<<<NB_TOTAL, 256, 0, stream>>>(xbA, xbF, xbI, xbP, wt,
                                            offs, cnt, csr,
                                            bA, bF, bI, bP, out);
  } else {
    fb_gemm<<<NBA, 256, 0, stream>>>(
        x_author, x_inst, x_paper, nullptr,
        wt + 0 * 16384, wt + 5 * 16384, wt + 7 * 16384, nullptr,
        3, B_ITA, B_PTA, 0, offs, cnt, csr, bA, out, N_AUTHOR);
    fb_gemm<<<NBF, 256, 0, stream>>>(
        x_fos, x_paper, nullptr, nullptr,
        wt + 1 * 16384, wt + 9 * 16384, nullptr, nullptr,
        2, B_TOPIC, 0, 0, offs, cnt, csr, bF, out + (size_t)100000 * 128, N_FOS);
    fb_gemm<<<NBI, 256, 0, stream>>>(
        x_inst, x_author, nullptr, nullptr,
        wt + 2 * 16384, wt + 4 * 16384, nullptr, nullptr,
        2, B_AFF, 0, 0, offs, cnt, csr, bI, out + (size_t)130000 * 128, N_INST);
    fb_gemm<<<NBP, 256, 0, stream>>>(
        x_paper, x_author, x_paper, x_fos,
        wt + 3 * 16384, wt + 6 * 16384, wt + 8 * 16384, wt + 10 * 16384,
        4, B_WRITES, B_CITES, B_FTP, offs, cnt, csr, bP,
        out + (size_t)138000 * 128, N_PAPER);
  }
}

// Round 18
// 806.170 us; speedup vs baseline: 1.2242x; 1.0496x over previous
//
#include <hip/hip_runtime.h>

#define N_AUTHOR 100000
#define N_FOS    30000
#define N_INST   8000
#define N_PAPER  200000
#define NCNT     838000
#define ETOT     3300000
#define NSHARD   (NCNT / 8)

#define NBA 1563
#define NBF 469
#define NBI 125
#define NBP 3125
#define NB_TOTAL (NBP + NBA + NBF + NBI)

#define B_AFF    0
#define B_ITA    8000
#define B_WRITES 108000
#define B_PTA    308000
#define B_CITES  408000
#define B_TOPIC  608000
#define B_FTP    638000

typedef __attribute__((ext_vector_type(8))) short short8v;
typedef __attribute__((ext_vector_type(4))) float float4v;
typedef unsigned short us;

__device__ __forceinline__ us f2bf(float f) {
  unsigned u = __float_as_uint(f);
  u = u + 0x7fffu + ((u >> 16) & 1u);
  return (us)(u >> 16);
}
#define BF2F(s) __uint_as_float(((unsigned)(us)(s)) << 16)

__device__ __forceinline__ void acc8(float4v& x, float4v& y, short8v h) {
  x[0] += BF2F(h[0]); x[1] += BF2F(h[1]); x[2] += BF2F(h[2]); x[3] += BF2F(h[3]);
  y[0] += BF2F(h[4]); y[1] += BF2F(h[5]); y[2] += BF2F(h[6]); y[3] += BF2F(h[7]);
}

__device__ __forceinline__ short8v pack8(float4v a, float4v b) {
  short8v h;
  h[0] = (short)f2bf(a[0]); h[1] = (short)f2bf(a[1]);
  h[2] = (short)f2bf(a[2]); h[3] = (short)f2bf(a[3]);
  h[4] = (short)f2bf(b[0]); h[5] = (short)f2bf(b[1]);
  h[6] = (short)f2bf(b[2]); h[7] = (short)f2bf(b[3]);
  return h;
}

// ---------------- workspace layout (bytes) ----------------
#define O_CNT    0
#define O_OFFS   3352000
#define O_CURSOR 6704000
#define O_BTOT   10056000
#define O_CSR    10060096
#define O_WT     23260096
#define XB_AUTHOR 23620544
#define XB_FOS    49220544
#define XB_INST   56900544
#define XB_PAPER  58948544
#define WS_NEED_BF 110148544ULL

struct RelTab { const int* src; const int* dst; int E; int base; };
struct Rels { RelTab r[7]; };
struct WPtrs { const float* w[11]; };
struct XCvt { const float* x; us* xb; int n8; };

// prep: W transpose+bf16, x fp32->bf16, XCD-sharded edge counting.
__global__ __launch_bounds__(256, 8) void prep(WPtrs P, us* __restrict__ wt,
                     int* __restrict__ cnt,
                     XCvt x0, XCvt x1, XCvt x2, XCvt x3,
                     Rels R, int doX) {
  int gsz = gridDim.x * blockDim.x;
  int gtid = blockIdx.x * blockDim.x + threadIdx.x;
  for (int i = gtid; i < 11 * 16384; i += gsz) {
    int mat = i >> 14, rem = i & 16383;
    int k = rem >> 7, n = rem & 127;
    wt[mat * 16384 + n * 128 + k] = f2bf(P.w[mat][rem]);
  }
  if (doX) {
    XCvt xc[4] = {x0, x1, x2, x3};
    #pragma unroll
    for (int a = 0; a < 4; ++a) {
      const float* xp = xc[a].x;
      short8v* xbp = (short8v*)xc[a].xb;
      int n8 = xc[a].n8;
      for (int i = gtid; i < n8; i += gsz) {
        float4v v0 = *(const float4v*)(xp + (size_t)i * 8);
        float4v v1 = *(const float4v*)(xp + (size_t)i * 8 + 4);
        xbp[i] = pack8(v0, v1);
      }
    }
  }
  const int cls = blockIdx.x & 7;
  const int lo = cls * NSHARD;
  const int hi = lo + NSHARD;
  const int sgsz = (gridDim.x >> 3) * 256;
  const int sgtid = (blockIdx.x >> 3) * 256 + threadIdx.x;
  #pragma unroll
  for (int rr = 0; rr < 7; ++rr) {
    const int* __restrict__ dst = R.r[rr].dst;
    const int E = R.r[rr].E, base = R.r[rr].base;
    for (int e = sgtid; e < E; e += sgsz) {
      int gd = base + dst[e];
      if (gd >= lo && gd < hi) atomicAdd(&cnt[gd], 1);
    }
  }
}

__global__ void scan1(const int* __restrict__ cnt, int* __restrict__ offs,
                      int* __restrict__ btot, int n) {
  __shared__ int sh[256];
  int tid = threadIdx.x;
  int base = blockIdx.x * 2048 + tid * 8;
  int v[8]; int s = 0;
  #pragma unroll
  for (int i = 0; i < 8; ++i) { v[i] = (base + i < n) ? cnt[base + i] : 0; s += v[i]; }
  sh[tid] = s; __syncthreads();
  for (int off = 1; off < 256; off <<= 1) {
    int t = (tid >= off) ? sh[tid - off] : 0;
    __syncthreads();
    sh[tid] += t;
    __syncthreads();
  }
  int excl = sh[tid] - s;
  if (tid == 255) btot[blockIdx.x] = sh[255];
  int run = excl;
  #pragma unroll
  for (int i = 0; i < 8; ++i) { if (base + i < n) offs[base + i] = run; run += v[i]; }
}

__global__ void scan23(int* __restrict__ offs, int* __restrict__ cursor,
                       const int* __restrict__ btot, int nb, int n) {
  __shared__ int sh[512];
  int tid = threadIdx.x;
  int v = (tid < nb) ? btot[tid] : 0;
  sh[tid] = v; __syncthreads();
  for (int off = 1; off < 512; off <<= 1) {
    int t = (tid >= off) ? sh[tid - off] : 0;
    __syncthreads();
    sh[tid] += t;
    __syncthreads();
  }
  int excl = sh[tid] - v;
  __syncthreads();
  sh[tid] = excl;
  __syncthreads();
  int gsz = gridDim.x * 512;
  for (int idx = blockIdx.x * 512 + tid; idx < n; idx += gsz) {
    int val = offs[idx] + sh[idx >> 11];
    offs[idx] = val;
    cursor[idx] = val;
  }
}

__global__ __launch_bounds__(256, 8) void fill_sh(Rels R, int* __restrict__ cursor,
                                                  int* __restrict__ csr) {
  const int cls = blockIdx.x & 7;
  const int lo = cls * NSHARD;
  const int hi = lo + NSHARD;
  const int gsz = (gridDim.x >> 3) * 256;
  const int gtid = (blockIdx.x >> 3) * 256 + threadIdx.x;
  #pragma unroll
  for (int rr = 0; rr < 7; ++rr) {
    const int* __restrict__ src = R.r[rr].src;
    const int* __restrict__ dst = R.r[rr].dst;
    const int E = R.r[rr].E, base = R.r[rr].base;
    for (int e = gtid; e < E; e += gsz) {
      int gd = base + dst[e];
      if (gd >= lo && gd < hi) {
        int p = atomicAdd(&cursor[gd], 1);
        csr[p] = src[e];
      }
    }
  }
}

// -------- fused gather-GEMM body: R12 2-edge batching (proven 466us) --------
template <int NSRC>
__device__ __forceinline__ void fused_body(
    const us* __restrict__ x0, const us* __restrict__ x1,
    const us* __restrict__ x2, const us* __restrict__ x3,
    const us* __restrict__ w0, const us* __restrict__ w1,
    const us* __restrict__ w2, const us* __restrict__ w3,
    int b1, int b2, int b3,
    const int* __restrict__ offs, const int* __restrict__ cnt,
    const int* __restrict__ csr,
    const float* __restrict__ bias, float* __restrict__ out, int n, int rb0) {
  const int lane = threadIdx.x & 63;
  const int wv = threadIdx.x >> 6;
  const int rb = rb0 + wv * 16;
  int ar = rb + (lane & 15); if (ar >= n) ar = n - 1;
  const int cw = (lane >> 4) * 8;

  const us* xs[4] = {x0, x1, x2, x3};
  const us* wsp[4] = {w0, w1, w2, w3};
  const int bases[4] = {0, b1, b2, b3};

  float4v acc[8];
  #pragma unroll
  for (int i = 0; i < 8; ++i) acc[i] = (float4v)0.0f;

  #pragma unroll
  for (int kb = 0; kb < NSRC; ++kb) {
    short8v af[4];
    if (kb == 0) {
      const us* rp = xs[0] + (size_t)ar * 128 + cw;
      #pragma unroll
      for (int ks = 0; ks < 4; ++ks)
        af[ks] = *(const short8v*)(rp + ks * 32);
    } else {
      int gd = bases[kb] + ar;
      int st = offs[gd];
      int deg = cnt[gd];
      const us* xb = xs[kb];
      float4v a0[4], a1[4];
      #pragma unroll
      for (int ks = 0; ks < 4; ++ks) { a0[ks] = (float4v)0.f; a1[ks] = (float4v)0.f; }
      int j = 0;
      for (; j + 2 <= deg; j += 2) {
        int s0 = csr[st + j], s1 = csr[st + j + 1];
        const us* p0 = xb + (size_t)s0 * 128 + cw;
        const us* p1 = xb + (size_t)s1 * 128 + cw;
        #pragma unroll
        for (int ks = 0; ks < 4; ++ks) {
          short8v h0 = *(const short8v*)(p0 + ks * 32);
          short8v h1 = *(const short8v*)(p1 + ks * 32);
          acc8(a0[ks], a1[ks], h0);
          acc8(a0[ks], a1[ks], h1);
        }
      }
      if (j < deg) {
        int s0 = csr[st + j];
        const us* p0 = xb + (size_t)s0 * 128 + cw;
        #pragma unroll
        for (int ks = 0; ks < 4; ++ks) {
          short8v h0 = *(const short8v*)(p0 + ks * 32);
          acc8(a0[ks], a1[ks], h0);
        }
      }
      float sc = 1.0f / (float)((deg > 0) ? deg : 1);
      #pragma unroll
      for (int ks = 0; ks < 4; ++ks)
        af[ks] = pack8(a0[ks] * sc, a1[ks] * sc);
    }
    const us* wb = wsp[kb] + (size_t)(lane & 15) * 128 + cw;
    #pragma unroll
    for (int ct = 0; ct < 8; ++ct) {
      short8v bfr[4];
      #pragma unroll
      for (int ks = 0; ks < 4; ++ks)
        bfr[ks] = *(const short8v*)(wb + ct * 2048 + ks * 32);
      #pragma unroll
      for (int ks = 0; ks < 4; ++ks)
        acc[ct] = __builtin_amdgcn_mfma_f32_16x16x32_bf16(af[ks], bfr[ks], acc[ct], 0, 0, 0);
    }
  }
  #pragma unroll
  for (int ct = 0; ct < 8; ++ct) {
    #pragma unroll
    for (int i = 0; i < 4; ++i) {
      int g = rb + (lane >> 4) * 4 + i;
      if (g < n) {
        int col = ct * 16 + (lane & 15);
        out[(size_t)g * 128 + col] = acc[ct][i] + bias[col];
      }
    }
  }
}

__global__ __launch_bounds__(256, 6) void fused_all(
    const us* __restrict__ xbA, const us* __restrict__ xbF,
    const us* __restrict__ xbI, const us* __restrict__ xbP,
    const us* __restrict__ wt,
    const int* __restrict__ offs, const int* __restrict__ cnt,
    const int* __restrict__ csr,
    const float* __restrict__ bA, const float* __restrict__ bF,
    const float* __restrict__ bI, const float* __restrict__ bP,
    float* __restrict__ out) {
  const int bid = blockIdx.x;
  if (bid < NBP) {
    fused_body<4>(xbP, xbA, xbP, xbF,
                  wt + 3 * 16384, wt + 6 * 16384, wt + 8 * 16384, wt + 10 * 16384,
                  B_WRITES, B_CITES, B_FTP, offs, cnt, csr,
                  bP, out + (size_t)138000 * 128, N_PAPER, bid * 64);
  } else if (bid < NBP + NBA) {
    fused_body<3>(xbA, xbI, xbP, nullptr,
                  wt + 0 * 16384, wt + 5 * 16384, wt + 7 * 16384, nullptr,
                  B_ITA, B_PTA, 0, offs, cnt, csr,
                  bA, out, N_AUTHOR, (bid - NBP) * 64);
  } else if (bid < NBP + NBA + NBF) {
    fused_body<2>(xbF, xbP, nullptr, nullptr,
                  wt + 1 * 16384, wt + 9 * 16384, nullptr, nullptr,
                  B_TOPIC, 0, 0, offs, cnt, csr,
                  bF, out + (size_t)100000 * 128, N_FOS, (bid - NBP - NBA) * 64);
  } else {
    fused_body<2>(xbI, xbA, nullptr, nullptr,
                  wt + 2 * 16384, wt + 4 * 16384, nullptr, nullptr,
                  B_AFF, 0, 0, offs, cnt, csr,
                  bI, out + (size_t)130000 * 128, N_INST, (bid - NBP - NBA - NBF) * 64);
  }
}

// ---------------- fp32 fallback (small ws) ----------------------------------
typedef float4v f4;
__global__ __launch_bounds__(256, 4) void fb_gemm(
    const float* __restrict__ x0, const float* __restrict__ x1,
    const float* __restrict__ x2, const float* __restrict__ x3,
    const us* __restrict__ w0, const us* __restrict__ w1,
    const us* __restrict__ w2, const us* __restrict__ w3,
    int nsrc, int b1, int b2, int b3,
    const int* __restrict__ offs, const int* __restrict__ cnt,
    const int* __restrict__ csr,
    const float* __restrict__ bias, float* __restrict__ out, int n) {
  const int lane = threadIdx.x & 63;
  const int wv = threadIdx.x >> 6;
  const int rb = blockIdx.x * 64 + wv * 16;
  int ar = rb + (lane & 15); if (ar >= n) ar = n - 1;
  const int cw = (lane >> 4) * 8;
  const float* xs[4] = {x0, x1, x2, x3};
  const us* wsp[4] = {w0, w1, w2, w3};
  const int bases[4] = {0, b1, b2, b3};
  float4v acc[8];
  #pragma unroll
  for (int i = 0; i < 8; ++i) acc[i] = (float4v)0.0f;
  for (int kb = 0; kb < nsrc; ++kb) {
    short8v af[4];
    const float* xb = xs[kb];
    if (kb == 0) {
      const float* rp = xb + (size_t)ar * 128 + cw;
      #pragma unroll
      for (int ks = 0; ks < 4; ++ks) {
        f4 u = *(const f4*)(rp + ks * 32);
        f4 v = *(const f4*)(rp + ks * 32 + 4);
        af[ks] = pack8(u, v);
      }
    } else {
      int gd = bases[kb] + ar;
      int st = offs[gd];
      int deg = cnt[gd];
      f4 a0[4], a1[4];
      #pragma unroll
      for (int ks = 0; ks < 4; ++ks) { a0[ks] = (f4)0.f; a1[ks] = (f4)0.f; }
      for (int j = 0; j < deg; ++j) {
        int s0 = csr[st + j];
        const float* p0 = xb + (size_t)s0 * 128 + cw;
        #pragma unroll
        for (int ks = 0; ks < 4; ++ks) {
          a0[ks] += *(const f4*)(p0 + ks * 32);
          a1[ks] += *(const f4*)(p0 + ks * 32 + 4);
        }
      }
      float sc = 1.0f / (float)((deg > 0) ? deg : 1);
      #pragma unroll
      for (int ks = 0; ks < 4; ++ks)
        af[ks] = pack8(a0[ks] * sc, a1[ks] * sc);
    }
    const us* wb = wsp[kb] + (size_t)(lane & 15) * 128 + cw;
    #pragma unroll
    for (int ct = 0; ct < 8; ++ct) {
      short8v bfr[4];
      #pragma unroll
      for (int ks = 0; ks < 4; ++ks)
        bfr[ks] = *(const short8v*)(wb + ct * 2048 + ks * 32);
      #pragma unroll
      for (int ks = 0; ks < 4; ++ks)
        acc[ct] = __builtin_amdgcn_mfma_f32_16x16x32_bf16(af[ks], bfr[ks], acc[ct], 0, 0, 0);
    }
  }
  #pragma unroll
  for (int ct = 0; ct < 8; ++ct) {
    #pragma unroll
    for (int i = 0; i < 4; ++i) {
      int g = rb + (lane >> 4) * 4 + i;
      if (g < n) {
        int col = ct * 16 + (lane & 15);
        out[(size_t)g * 128 + col] = acc[ct][i] + bias[col];
      }
    }
  }
}

extern "C" void kernel_launch(void* const* d_in, const int* in_sizes, int n_in,
                              void* d_out, int out_size, void* d_ws, size_t ws_size,
                              hipStream_t stream) {
  const float* x_author = (const float*)d_in[0];
  const float* x_fos    = (const float*)d_in[1];
  const float* x_inst   = (const float*)d_in[2];
  const float* x_paper  = (const float*)d_in[3];

  Rels R;
  const int E[7]  = {150000, 150000, 500000, 500000, 1000000, 500000, 500000};
  const int ND[7] = {N_INST, N_AUTHOR, N_PAPER, N_AUTHOR, N_PAPER, N_FOS, N_PAPER};
  int base = 0;
  for (int r = 0; r < 7; ++r) {
    R.r[r].src = (const int*)d_in[4 + 2 * r];
    R.r[r].dst = (const int*)d_in[5 + 2 * r];
    R.r[r].E = E[r];
    R.r[r].base = base;
    base += ND[r];
  }

  char* ws = (char*)d_ws;
  int* cnt    = (int*)(ws + O_CNT);
  int* offs   = (int*)(ws + O_OFFS);
  int* cursor = (int*)(ws + O_CURSOR);
  int* btot   = (int*)(ws + O_BTOT);
  int* csr    = (int*)(ws + O_CSR);
  us* wt  = (us*)(ws + O_WT);
  us* xbA = (us*)(ws + XB_AUTHOR);
  us* xbF = (us*)(ws + XB_FOS);
  us* xbI = (us*)(ws + XB_INST);
  us* xbP = (us*)(ws + XB_PAPER);

  const int useBF = (ws_size >= WS_NEED_BF) ? 1 : 0;

  WPtrs WP;
  WP.w[0] = (const float*)d_in[18];
  WP.w[1] = (const float*)d_in[20];
  WP.w[2] = (const float*)d_in[22];
  WP.w[3] = (const float*)d_in[24];
  for (int r = 0; r < 7; ++r) WP.w[4 + r] = (const float*)d_in[26 + r];

  XCvt xcA = {x_author, xbA, N_AUTHOR * 16};
  XCvt xcF = {x_fos,    xbF, N_FOS * 16};
  XCvt xcI = {x_inst,   xbI, N_INST * 16};
  XCvt xcP = {x_paper,  xbP, N_PAPER * 16};

  hipMemsetAsync(cnt, 0, (size_t)NCNT * 4, stream);
  prep<<<2048, 256, 0, stream>>>(WP, wt, cnt, xcA, xcF, xcI, xcP, R, useBF);
  scan1<<<410, 256, 0, stream>>>(cnt, offs, btot, NCNT);
  scan23<<<1024, 512, 0, stream>>>(offs, cursor, btot, 410, NCNT);
  fill_sh<<<2048, 256, 0, stream>>>(R, cursor, csr);

  float* out = (float*)d_out;
  const float* bA = (const float*)d_in[19];
  const float* bF = (const float*)d_in[21];
  const float* bI = (const float*)d_in[23];
  const float* bP = (const float*)d_in[25];

  if (useBF) {
    fused_all<<<NB_TOTAL, 256, 0, stream>>>(xbA, xbF, xbI, xbP, wt,
                                            offs, cnt, csr,
                                            bA, bF, bI, bP, out);
  } else {
    fb_gemm<<<NBA, 256, 0, stream>>>(
        x_author, x_inst, x_paper, nullptr,
        wt + 0 * 16384, wt + 5 * 16384, wt + 7 * 16384, nullptr,
        3, B_ITA, B_PTA, 0, offs, cnt, csr, bA, out, N_AUTHOR);
    fb_gemm<<<NBF, 256, 0, stream>>>(
        x_fos, x_paper, nullptr, nullptr,
        wt + 1 * 16384, wt + 9 * 16384, nullptr, nullptr,
        2, B_TOPIC, 0, 0, offs, cnt, csr, bF, out + (size_t)100000 * 128, N_FOS);
    fb_gemm<<<NBI, 256, 0, stream>>>(
        x_inst, x_author, nullptr, nullptr,
        wt + 2 * 16384, wt + 4 * 16384, nullptr, nullptr,
        2, B_AFF, 0, 0, offs, cnt, csr, bI, out + (size_t)130000 * 128, N_INST);
    fb_gemm<<<NBP, 256, 0, stream>>>(
        x_paper, x_author, x_paper, x_fos,
        wt + 3 * 16384, wt + 6 * 16384, wt + 8 * 16384, wt + 10 * 16384,
        4, B_WRITES, B_CITES, B_FTP, offs, cnt, csr, bP,
        out + (size_t)138000 * 128, N_PAPER);
  }
}